// Round 2
// baseline (52.847 us; speedup 1.0000x reference)
//
#include <hip/hip_runtime.h>
#include <hip/hip_bf16.h>
#include <hip/hip_fp16.h>
#include <stdint.h>

// GGUF Q6_K fused dequant + GEMM:  out[16,14336] = x[16,4096] . W^T + bias
// NOTE: the harness materializes the uint8 w_q array as int32 (one byte-value
// per dword, 192.7 MB) -- we load int4 (4 dwords), repack low bytes to one
// dword in registers, and stage packed bytes into LDS. Downstream: per-lane
// SWAR nibble dequant -> bf16 -> mfma_f32_16x16x32_bf16 (M=16 batch, N=16
// rows, K=32). K-split 8 via f32 atomicAdd; bias pre-filled by prep kernel.

#define OUT_F 14336
#define IN_F  4096
#define NB    16

using f32x4  = __attribute__((ext_vector_type(4))) float;
using short8 = __attribute__((ext_vector_type(8))) short;

constexpr int ROWS = 64;                  // output rows per block
constexpr int SBS  = 2;                   // super-blocks (256 k each) per block
constexpr int SLOT = 216;                 // LDS bytes per sb slot (210 + pad, 8-aligned)
constexpr int ROWSTRIDE = SBS * SLOT + 8; // 440 bytes per row in LDS
constexpr int KSPLIT = IN_F / (SBS * 256); // 8

__device__ __forceinline__ float ub(uint32_t v, int i) {
  return (float)((v >> (8 * i)) & 0xffu);   // -> v_cvt_f32_ubyteN
}
__device__ __forceinline__ uint32_t pack_bf16(float lo, float hi) {
  return (__builtin_bit_cast(uint32_t, lo) >> 16) |
         (__builtin_bit_cast(uint32_t, hi) & 0xffff0000u);
}

__global__ __launch_bounds__(256)
void prep_kernel(const float* __restrict__ x, const float* __restrict__ bias,
                 float* __restrict__ out, ushort* __restrict__ xbf, int use_ws)
{
  const int t = blockIdx.x * 256 + threadIdx.x;
  if (t < NB * OUT_F) {
    out[t] = bias[t % OUT_F];              // init output with bias; GEMM atomically adds
  }
  if (use_ws && t < NB * IN_F) {
    uint32_t u = __builtin_bit_cast(uint32_t, x[t]);
    xbf[t] = (ushort)((u + 0x8000u) >> 16); // f32 -> bf16
  }
}

template<bool USE_WS>
__global__ __launch_bounds__(256, 4)
void q6k_gemm(const int* __restrict__ wq,          // int32: one byte-value per dword
              const float* __restrict__ xf,
              const ushort* __restrict__ xbf,
              float* __restrict__ out)
{
  __shared__ uint8_t lds[ROWS * ROWSTRIDE];
  const int tid = threadIdx.x;
  const int bx  = blockIdx.x;      // 0..223  (row tile)
  const int by  = blockIdx.y;      // 0..7    (k split)
  const int row_base = bx * ROWS;

  // ---- stage: 64 rows x 420 byte-values (= 420 dwords) -> packed, realigned LDS ----
  ushort* lds16 = (ushort*)lds;
  for (int i = tid; i < ROWS * 105; i += 256) {
    const int r = i / 105;
    const int d = i - r * 105;
    const int4 q4 = *(const int4*)(wq + (size_t)(row_base + r) * 3360 + by * 420 + 4 * d);
    const uint32_t v = (uint32_t)(q4.x & 0xff) | ((uint32_t)(q4.y & 0xff) << 8) |
                       ((uint32_t)(q4.z & 0xff) << 16) | ((uint32_t)q4.w << 24);
    const int b0 = 4 * d, b1 = 4 * d + 2;
    const int sb0 = b0 / 210, sb1 = b1 / 210;       // handles 210-byte boundary straddle
    lds16[(r * ROWSTRIDE + sb0 * SLOT + (b0 - sb0 * 210)) >> 1] = (ushort)v;
    lds16[(r * ROWSTRIDE + sb1 * SLOT + (b1 - sb1 * 210)) >> 1] = (ushort)(v >> 16);
  }
  __syncthreads();

  const int lane = tid & 63;
  const int wv   = tid >> 6;       // wave 0..3 -> owns 16 rows
  const int l15  = lane & 15;
  const int lg   = lane >> 4;      // 0..3 (k-octet group)
  const int sc_sh = 8 * (lane >> 5);

  f32x4 acc = {0.f, 0.f, 0.f, 0.f};
  const int k_blk = by * (SBS * 256);
  const uint8_t* rowslot = lds + (wv * 16 + l15) * ROWSTRIDE;

  #pragma unroll
  for (int sb = 0; sb < SBS; ++sb) {
    const uint8_t* slot = rowslot + sb * SLOT;
    const uint2 sc01 = *(const uint2*)(slot + 192);   // scales 0..7
    const uint2 sc23 = *(const uint2*)(slot + 200);   // scales 8..15
    const float dsup = __half2float(*(const __half*)(slot + 208));
    const int k_sb = k_blk + sb * 256 + 8 * lg;

    #pragma unroll
    for (int m = 0; m < 8; ++m) {
      // element run e0 = 32m + 8*lg, 8 consecutive elements
      const uint2 ql = *(const uint2*)(slot + (m >> 2) * 64 + (m & 1) * 32 + 8 * lg);
      const uint2 qh = *(const uint2*)(slot + 128 + (m >> 2) * 32 + 8 * lg);

      const uint32_t scw = (m >> 1) == 0 ? sc01.x : (m >> 1) == 1 ? sc01.y
                         : (m >> 1) == 2 ? sc23.x : sc23.y;
      const int sc = (int)(int8_t)(scw >> (16 * (m & 1) + sc_sh));
      const float dl  = dsup * (float)sc;
      const float mdl = -32.0f * dl;

      const int SL = 4 * ((m >> 1) & 1);
      const int SH = 2 * (m & 3);
      const uint32_t t0 = (ql.x >> SL) & 0x0F0F0F0Fu;
      const uint32_t t1 = (ql.y >> SL) & 0x0F0F0F0Fu;
      const uint32_t h0 = (qh.x >> SH) & 0x03030303u;
      const uint32_t h1 = (qh.y >> SH) & 0x03030303u;
      const uint32_t q0 = t0 | (h0 << 4);
      const uint32_t q1 = t1 | (h1 << 4);

      const float w0 = fmaf(ub(q0, 0), dl, mdl);
      const float w1 = fmaf(ub(q0, 1), dl, mdl);
      const float w2 = fmaf(ub(q0, 2), dl, mdl);
      const float w3 = fmaf(ub(q0, 3), dl, mdl);
      const float w4 = fmaf(ub(q1, 0), dl, mdl);
      const float w5 = fmaf(ub(q1, 1), dl, mdl);
      const float w6 = fmaf(ub(q1, 2), dl, mdl);
      const float w7 = fmaf(ub(q1, 3), dl, mdl);

      union { short8 s; uint32_t u[4]; } bfr;
      bfr.u[0] = pack_bf16(w0, w1);
      bfr.u[1] = pack_bf16(w2, w3);
      bfr.u[2] = pack_bf16(w4, w5);
      bfr.u[3] = pack_bf16(w6, w7);

      short8 afrag;
      if constexpr (USE_WS) {
        afrag = *(const short8*)(xbf + (size_t)l15 * IN_F + k_sb + m * 32);
      } else {
        const float* xp = xf + (size_t)l15 * IN_F + k_sb + m * 32;
        const f32x4 v0 = *(const f32x4*)(xp);
        const f32x4 v1 = *(const f32x4*)(xp + 4);
        union { short8 s; uint32_t u[4]; } av;
        av.u[0] = pack_bf16(v0[0], v0[1]);
        av.u[1] = pack_bf16(v0[2], v0[3]);
        av.u[2] = pack_bf16(v1[0], v1[1]);
        av.u[3] = pack_bf16(v1[2], v1[3]);
        afrag = av.s;
      }

      acc = __builtin_amdgcn_mfma_f32_16x16x32_bf16(afrag, bfr.s, acc, 0, 0, 0);
    }
  }

  // C/D layout (m89-verified): col = lane&15 (output row), row = (lane>>4)*4 + reg (batch)
  const int o = row_base + wv * 16 + l15;
  #pragma unroll
  for (int r = 0; r < 4; ++r) {
    atomicAdd(&out[(size_t)(lg * 4 + r) * OUT_F + o], acc[r]);
  }
}

extern "C" void kernel_launch(void* const* d_in, const int* in_sizes, int n_in,
                              void* d_out, int out_size, void* d_ws, size_t ws_size,
                              hipStream_t stream)
{
  const float* x    = (const float*)d_in[0];
  const int*   wq   = (const int*)d_in[1];     // uint8 values materialized as int32
  const float* bias = (const float*)d_in[2];
  float*  out = (float*)d_out;
  ushort* xbf = (ushort*)d_ws;
  const bool use_ws = ws_size >= (size_t)NB * IN_F * 2;

  prep_kernel<<<dim3((NB * OUT_F + 255) / 256), dim3(256), 0, stream>>>(
      x, bias, out, xbf, use_ws ? 1 : 0);

  dim3 grid(OUT_F / ROWS, KSPLIT);
  if (use_ws) {
    q6k_gemm<true><<<grid, dim3(256), 0, stream>>>(wq, x, xbf, out);
  } else {
    q6k_gemm<false><<<grid, dim3(256), 0, stream>>>(wq, x, xbf, out);
  }
}